// Round 19
// baseline (496.594 us; speedup 1.0000x reference)
//
#include <hip/hip_runtime.h>

// DMMRLoss_52621939310662 — round 19: r16 base (conv2 reverted to scalar
// broadcast form; r18's W2T4/b128 conv2 regressed) + single-pass conv1.
// Changes vs r16:
//  - conv1 computes all 8 wave-channels (both halves, acc[8][8]) in ONE pass
//    over (ic,td,th): each volume staged ONCE (2 stagings vs 4), conv1 LDS
//    reads halved (612 -> 306/thread).
//  - conv1-out streamed per half: write half0 -> conv2 half0 -> write half1
//    -> conv2 half1 (waves touch only their own slots).
//  - keep/fc2 reductions via wave shfl (fewer barriers).
// Spill canary: WRITE_SIZE must stay ~100s of bytes. VGPR target ~100-120.

static constexpr int kPS = 433;    // staging plane stride (4-way floor)
static constexpr int kRS = 25;     // staging row stride
static constexpr int kCS = 528;    // conv1-out channel stride
static constexpr int kZS = 66;     // conv1-out z stride (y stride = 8)
static constexpr int kHOff = 6912; // h[k] region after partials

template <bool WPACK>
static __device__ __forceinline__ float2 dmr19_patch(
    int p, int t,
    const float* __restrict__ src, const float* __restrict__ tgt,
    const float* __restrict__ c1w, const float* __restrict__ c1b,
    const float* __restrict__ c2w, const float* __restrict__ c2b,
    const float* __restrict__ fw1, const float* __restrict__ f1b,
    const float* __restrict__ f2w, const float* __restrict__ f2b,
    float* __restrict__ sBuf, float* __restrict__ sRed) {
  int pd = p / 169; int rem = p - pd * 169; int phh = rem / 13; int pww = rem - phh * 13;
  int z0 = pd * 17, y0 = phh * 17, x0 = pww * 17;

  int wv  = t >> 6;                   // wave 0..3
  int od  = (t >> 3) & 7, oh = t & 7;
  int oc2 = t & 63;

  // ---- stage tgt patch + count zeros (keep flag) ----
  float cnt = 0.f;
  for (int idx = t; idx < 4913; idx += 256) {
    int a = idx / 289; int r2 = idx - a * 289; int b = r2 / 17; int c = r2 - b * 17;
    float v = tgt[((size_t)(z0 + a) * 222 + (y0 + b)) * 222 + (x0 + c)];
    sBuf[a * kPS + b * kRS + c] = v;
    if (v == 0.0f) cnt += 1.f;
  }
  #pragma unroll
  for (int o = 32; o > 0; o >>= 1) cnt += __shfl_down(cnt, o, 64);
  if ((t & 63) == 0) sRed[wv] = cnt;
  __syncthreads();                    // also makes staged tgt visible
  float keep = ((sRed[0] + sRed[1] + sRed[2] + sRed[3]) / 4913.0f <= 0.5f) ? 1.0f : 0.0f;

  // ---- conv1: one pass, all 8 wave-channels (half0: wv*4+ocr, half1: 16+wv*4+ocr)
  float acc[8][8];
  #pragma unroll
  for (int i = 0; i < 8; i++)
    #pragma unroll
    for (int j = 0; j < 8; j++) acc[i][j] = 0.f;

  #pragma unroll 1
  for (int ic = 0; ic < 2; ic++) {
    if (ic == 1) {                    // stage src once
      __syncthreads();                // conv1 ic=0 reads done
      for (int idx = t; idx < 4913; idx += 256) {
        int a = idx / 289; int r2 = idx - a * 289; int b = r2 / 17; int c = r2 - b * 17;
        sBuf[a * kPS + b * kRS + c] =
            src[((size_t)(z0 + a) * 222 + (y0 + b)) * 222 + (x0 + c)];
      }
      __syncthreads();
    }
    #pragma unroll 1
    for (int td = 0; td < 3; td++) {
      #pragma unroll 1
      for (int th = 0; th < 3; th++) {
        int rbase = (2 * od + td) * kPS + (2 * oh + th) * kRS;
        float a[17];
        #pragma unroll
        for (int x = 0; x < 17; x++) a[x] = sBuf[rbase + x];
        #pragma unroll
        for (int hh = 0; hh < 2; hh++) {
          #pragma unroll
          for (int ocr = 0; ocr < 4; ocr++) {
            int oc = hh * 16 + wv * 4 + ocr;
            const float* wp = c1w + oc * 54 + ic * 27 + td * 9 + th * 3;
            float w0 = wp[0], w1 = wp[1], w2 = wp[2];
            #pragma unroll
            for (int ow = 0; ow < 8; ow++)
              acc[hh * 4 + ocr][ow] += a[2 * ow] * w0 + a[2 * ow + 1] * w1 + a[2 * ow + 2] * w2;
          }
        }
      }
    }
  }

  // ---- conv2 over two halves; conv1-out streamed per half ----
  float acc2[27];
  #pragma unroll
  for (int i = 0; i < 27; i++) acc2[i] = 0.f;

  #pragma unroll 1
  for (int hh = 0; hh < 2; hh++) {
    __syncthreads();                  // hh0: conv1 staging reads done; hh1: conv2 h0 reads done
    #pragma unroll
    for (int ocr = 0; ocr < 4; ocr++) {
      int lo = wv * 4 + ocr;
      float b = c1b[hh * 16 + lo];
      int base = lo * kCS + od * kZS + oh * 8;
      #pragma unroll
      for (int ow = 0; ow < 8; ow++)
        sBuf[base + ow] = fmaxf(acc[hh * 4 + ocr][ow] + b, 0.f);
    }
    __syncthreads();

    #pragma unroll 1
    for (int icr = 0; icr < 4; icr++) {
      int icl = wv * 4 + icr;
      int ic  = hh * 16 + icl;
      const float* cbase = sBuf + icl * kCS;
      #pragma unroll 1
      for (int td = 0; td < 3; td++) {
        #pragma unroll 1
        for (int th = 0; th < 3; th++) {
          const float* wp = c2w + oc2 * 864 + ic * 27 + td * 9 + th * 3;
          float w0 = wp[0], w1 = wp[1], w2 = wp[2];
          #pragma unroll
          for (int zo = 0; zo < 3; zo++) {
            #pragma unroll
            for (int yo = 0; yo < 3; yo++) {
              const float* rp = cbase + (2 * zo + td) * kZS + (2 * yo + th) * 8;
              #pragma unroll
              for (int xo = 0; xo < 3; xo++)
                acc2[zo * 9 + yo * 3 + xo] +=
                    rp[2 * xo] * w0 + rp[2 * xo + 1] * w1 + rp[2 * xo + 2] * w2;
            }
          }
        }
      }
    }
  }
  __syncthreads();
  // cross-wave reduce of conv2 partials: [wv][pos][oc] in [0, 6912)
  #pragma unroll
  for (int pos = 0; pos < 27; pos++)
    sBuf[(wv * 27 + pos) * 64 + oc2] = acc2[pos];
  __syncthreads();
  float* sH = sBuf + kHOff;           // h[k], k = o*27 + pos
  for (int idx = t; idx < 1728; idx += 256) {
    int o = idx & 63, pos = idx >> 6;
    float v = sBuf[pos * 64 + o] + sBuf[(27 + pos) * 64 + o] +
              sBuf[(54 + pos) * 64 + o] + sBuf[(81 + pos) * 64 + o];
    sH[o * 27 + pos] = fmaxf(v + c2b[o], 0.f);
  }
  __syncthreads();

  // ---- fc1 (n = t) + fc2 + tanh ----
  float acc1 = 0.f;
  if (WPACK) {
    const float4* w4p = (const float4*)fw1;          // W1T4[k4][n]
    const float4* sH4 = (const float4*)sH;
    #pragma unroll 8
    for (int k4 = 0; k4 < 432; k4++) {
      float4 w  = w4p[k4 * 256 + t];
      float4 hv = sH4[k4];
      acc1 += w.x * hv.x + w.y * hv.y + w.z * hv.z + w.w * hv.w;
    }
  } else {
    const float* frow = fw1 + (size_t)t * 1728;
    #pragma unroll 8
    for (int k = 0; k < 1728; k++) acc1 += sH[k] * frow[k];
  }
  float h = fmaxf(acc1 + f1b[t], 0.f);
  float tl = h * f2w[t];
  #pragma unroll
  for (int o = 32; o > 0; o >>= 1) tl += __shfl_down(tl, o, 64);
  if ((t & 63) == 0) sRed[wv] = tl;
  __syncthreads();
  float2 rk;
  rk.x = tanhf(sRed[0] + sRed[1] + sRed[2] + sRed[3] + f2b[0]) * keep;
  rk.y = keep;
  __syncthreads();                    // protect sRed/sBuf for callers that loop
  return rk;
}

// ---- pack f1w[n][k] -> W1T4[k4][n] ----
__global__ void dmr19_tr(const float* __restrict__ f1w, float* __restrict__ w1t4) {
  int k4 = blockIdx.x;                 // 0..431
  int n  = threadIdx.x;                // 0..255
  const float* s = f1w + (size_t)n * 1728 + k4 * 4;
  float4 w; w.x = s[0]; w.y = s[1]; w.z = s[2]; w.w = s[3];
  ((float4*)w1t4)[k4 * 256 + n] = w;
}

// ---- hot kernel (identifier-named): one patch per block, 4 blocks/CU ----
__global__ __launch_bounds__(256, 4)
void DMMRLoss_52621939310662_kernel(
    const float* __restrict__ src, const float* __restrict__ tgt,
    const float* __restrict__ c1w, const float* __restrict__ c1b,
    const float* __restrict__ c2w, const float* __restrict__ c2b,
    const float* __restrict__ w1t4, const float* __restrict__ f1b,
    const float* __restrict__ f2w, const float* __restrict__ f2b,
    float* __restrict__ pr, float* __restrict__ pk) {
  __shared__ float sBuf[8704];
  __shared__ float sRed[4];
  int t = threadIdx.x;
  float2 rk = dmr19_patch<true>(blockIdx.x, t, src, tgt, c1w, c1b, c2w, c2b,
                                w1t4, f1b, f2w, f2b, sBuf, sRed);
  if (t == 0) { pr[blockIdx.x] = rk.x; pk[blockIdx.x] = rk.y; }
}

// ---- raw hot fallback (ws too small for the pack) ----
__global__ __launch_bounds__(256, 4)
void dmr19_hot_raw(const float* __restrict__ src, const float* __restrict__ tgt,
                   const float* __restrict__ c1w, const float* __restrict__ c1b,
                   const float* __restrict__ c2w, const float* __restrict__ c2b,
                   const float* __restrict__ f1w, const float* __restrict__ f1b,
                   const float* __restrict__ f2w, const float* __restrict__ f2b,
                   float* __restrict__ pr, float* __restrict__ pk) {
  __shared__ float sBuf[8704];
  __shared__ float sRed[4];
  int t = threadIdx.x;
  float2 rk = dmr19_patch<false>(blockIdx.x, t, src, tgt, c1w, c1b, c2w, c2b,
                                 f1w, f1b, f2w, f2b, sBuf, sRed);
  if (t == 0) { pr[blockIdx.x] = rk.x; pk[blockIdx.x] = rk.y; }
}

// ---- final reduce -> float32 scalar ----
__global__ void dmr19_reduce(const float* __restrict__ pr, const float* __restrict__ pk,
                             float* __restrict__ out) {
  __shared__ float s1[256], s2[256];
  int t = threadIdx.x;
  float a = 0.f, b = 0.f;
  for (int p = t; p < 2197; p += 256) { a += pr[p]; b += pk[p]; }
  s1[t] = a; s2[t] = b;
  __syncthreads();
  for (int o = 128; o > 0; o >>= 1) {
    if (t < o) { s1[t] += s1[t + o]; s2[t] += s2[t + o]; }
    __syncthreads();
  }
  if (t == 0) out[0] = s1[0] / s2[0];
}

// ---- ws-free fallback: single block does everything ----
__global__ __launch_bounds__(256, 4)
void dmr19_solo(const float* __restrict__ src, const float* __restrict__ tgt,
                const float* __restrict__ c1w, const float* __restrict__ c1b,
                const float* __restrict__ c2w, const float* __restrict__ c2b,
                const float* __restrict__ f1w, const float* __restrict__ f1b,
                const float* __restrict__ f2w, const float* __restrict__ f2b,
                float* __restrict__ out) {
  __shared__ float sBuf[8704];
  __shared__ float sRed[4];
  __shared__ float sAcc[2];
  int t = threadIdx.x;
  if (t == 0) { sAcc[0] = 0.f; sAcc[1] = 0.f; }
  for (int p = 0; p < 2197; p++) {
    __syncthreads();
    float2 rk = dmr19_patch<false>(p, t, src, tgt, c1w, c1b, c2w, c2b,
                                   f1w, f1b, f2w, f2b, sBuf, sRed);
    if (t == 0) { sAcc[0] += rk.x; sAcc[1] += rk.y; }
  }
  __syncthreads();
  if (t == 0) out[0] = sAcc[0] / sAcc[1];
}

extern "C" void kernel_launch(void* const* d_in, const int* in_sizes, int n_in,
                              void* d_out, int out_size, void* d_ws, size_t ws_size,
                              hipStream_t stream) {
  const float* src = (const float*)d_in[0];   // source = moving
  const float* tgt = (const float*)d_in[1];   // target = fixed
  const float* c1w = (const float*)d_in[2];
  const float* c1b = (const float*)d_in[3];
  const float* c2w = (const float*)d_in[4];
  const float* c2b = (const float*)d_in[5];
  const float* f1w = (const float*)d_in[6];
  const float* f1b = (const float*)d_in[7];
  const float* f2w = (const float*)d_in[8];
  const float* f2b = (const float*)d_in[9];
  float* out = (float*)d_out;

  const size_t nW1T = 442368;                 // 1728*256
  const size_t nPK  = 2 * 2197;
  if (d_ws && ws_size >= (nW1T + nPK) * sizeof(float)) {
    float* w1t4 = (float*)d_ws;               // 16B-aligned at ws+0
    float* pr   = w1t4 + nW1T;
    float* pk   = pr + 2197;
    dmr19_tr<<<432, 256, 0, stream>>>(f1w, w1t4);
    DMMRLoss_52621939310662_kernel<<<2197, 256, 0, stream>>>(
        src, tgt, c1w, c1b, c2w, c2b, w1t4, f1b, f2w, f2b, pr, pk);
    dmr19_reduce<<<1, 256, 0, stream>>>(pr, pk, out);
  } else if (d_ws && ws_size >= nPK * sizeof(float)) {
    float* pr = (float*)d_ws;
    float* pk = pr + 2197;
    dmr19_hot_raw<<<2197, 256, 0, stream>>>(
        src, tgt, c1w, c1b, c2w, c2b, f1w, f1b, f2w, f2b, pr, pk);
    dmr19_reduce<<<1, 256, 0, stream>>>(pr, pk, out);
  } else {
    dmr19_solo<<<1, 256, 0, stream>>>(
        src, tgt, c1w, c1b, c2w, c2b, f1w, f1b, f2w, f2b, out);
  }
}